// Round 5
// baseline (861.304 us; speedup 1.0000x reference)
//
#include <hip/hip_runtime.h>
#include <stdint.h>
#include <stddef.h>

// ---------------- problem constants ----------------
constexpr int Dm  = 256;
constexpr int NH  = 8;
constexpr int NL  = 4;
constexpr int NP  = 4;
constexpr int DFF = 1024;
constexpr int Bb  = 2;
constexpr int Sn  = 21760;            // 128*128 + 64*64 + 32*32 + 16*16
constexpr int BS  = Bb * Sn;          // 43520  (= 340 * 128 exactly)
constexpr int DH  = Dm / NH;          // 32

// ---------------- small helpers ----------------
__device__ __forceinline__ unsigned short f2bf(float f) {
    union { float f; unsigned int u; } v; v.f = f;
    unsigned int u = v.u;
    unsigned int r = u + 0x7FFFu + ((u >> 16) & 1u);   // round-nearest-even
    return (unsigned short)(r >> 16);
}

typedef float  f32x4  __attribute__((ext_vector_type(4)));
typedef float  f32x2  __attribute__((ext_vector_type(2)));
typedef __bf16 bf16x8 __attribute__((ext_vector_type(8)));

// unpack 2 bf16 (packed in u32) -> float2
__device__ __forceinline__ f32x2 cvt2(unsigned int u) {
    union { unsigned int u; float f; } lo, hi;
    lo.u = u << 16; hi.u = u & 0xFFFF0000u;
    f32x2 r; r.x = lo.f; r.y = hi.f; return r;
}

// address-space helpers for global_load_lds
typedef const __attribute__((address_space(1))) unsigned int GU;
typedef __attribute__((address_space(3))) unsigned int LU;
__device__ __forceinline__ void g2lds16(const void* g, void* l) {
    __builtin_amdgcn_global_load_lds((GU*)g, (LU*)l, 16, 0, 0);
}

// ---------------- all weights: convert + transpose in ONE kernel ----------------
// wT element layout (all N-major, [n][k]):
//   WprojT @0       : 640 x 256  (cols 0-255 W_val, 256-511 W_off, 512-639 W_attn)
//   WoutT  @163840  : 256 x 256
//   Wffn1T @229376  : 1024 x 256
//   Wffn2T @491520  : 256 x 1024
__global__ void transpose_all(const float* __restrict__ W_val, const float* __restrict__ W_off,
                              const float* __restrict__ W_attn, const float* __restrict__ W_out,
                              const float* __restrict__ W_ffn1, const float* __restrict__ W_ffn2,
                              unsigned short* __restrict__ wT) {
    int i = blockIdx.x * 256 + threadIdx.x;
    float v;
    if (i < 163840) {                       // proj block
        int n = i >> 8, k = i & 255;
        if      (n < 256) v = W_val[(size_t)k * 256 + n];
        else if (n < 512) v = W_off[(size_t)k * 256 + (n - 256)];
        else              v = W_attn[(size_t)k * 128 + (n - 512)];
    } else if (i < 229376) {
        int j = i - 163840, n = j >> 8, k = j & 255;
        v = W_out[(size_t)k * 256 + n];
    } else if (i < 491520) {
        int j = i - 229376, n = j >> 8, k = j & 255;
        v = W_ffn1[(size_t)k * 1024 + n];
    } else if (i < 753664) {
        int j = i - 491520, n = j >> 10, k = j & 1023;
        v = W_ffn2[(size_t)k * 256 + n];
    } else return;
    wT[i] = f2bf(v);
}

// ---------------- q = src+pos (bf16), src (bf16), float4-vectorized ----------------
__global__ void prep_q(const float* __restrict__ src, const float* __restrict__ pos,
                       unsigned short* __restrict__ srcb, unsigned short* __restrict__ qb,
                       int ntot) {
    for (int i = (blockIdx.x * blockDim.x + threadIdx.x) * 4; i < ntot;
         i += gridDim.x * blockDim.x * 4) {
        const float4 s = *(const float4*)&src[i];
        const float4 p = *(const float4*)&pos[i];
        ushort4 sb, qb4;
        sb.x = f2bf(s.x); sb.y = f2bf(s.y); sb.z = f2bf(s.z); sb.w = f2bf(s.w);
        qb4.x = f2bf(s.x + p.x); qb4.y = f2bf(s.y + p.y);
        qb4.z = f2bf(s.z + p.z); qb4.w = f2bf(s.w + p.w);
        *(ushort4*)&srcb[i] = sb;
        *(ushort4*)&qb[i]   = qb4;
    }
}

// ---------------- fused projection GEMM: value + offsets + attn(softmax) ----------------
// v4: 256x128 tiles (2x M vs v2), K=256, grid (5, 170). Halves block count,
// doubles L2 B-reuse, 32 MFMA / 12 ds_read / 6 stage-loads per wave-K-step.
// Single-buffer 2-barrier loop (best-measured structure) + XOR chunk swizzle.
__global__ __launch_bounds__(256)
void gemm_proj(const unsigned short* __restrict__ srcb,
               const unsigned short* __restrict__ qb,
               const unsigned short* __restrict__ WprojT,
               const float* __restrict__ b_val, const float* __restrict__ b_off,
               const float* __restrict__ b_attn, const float* __restrict__ refpts,
               unsigned short* __restrict__ valb, float* __restrict__ locf,
               float* __restrict__ attnf)
{
    __shared__ __align__(16) unsigned short As[256 * 32];   // 16 KB
    __shared__ __align__(16) unsigned short Bs[128 * 32];   // 8 KB

    const int tid  = threadIdx.x;
    const int lane = tid & 63;
    const int w    = tid >> 6;
    const int quad = lane >> 4;
    const int r16  = lane & 15;
    const int wr   = w >> 1, wc = w & 1;    // wave: rows wr*128..+127, cols wc*64..+63
    const int bm   = blockIdx.y, bn = blockIdx.x;

    const unsigned short* A  = (bn < 2) ? srcb : qb;
    const unsigned short* BT = WprojT + (size_t)bn * 128 * 256;

    const int sr = tid >> 2;
    const int sw = (((tid & 3) ^ ((tid >> 3) & 3)) << 3);
    const int qx = ((quad ^ ((r16 >> 1) & 3)) << 3);

    const unsigned short* gA0 = A  + (size_t)(bm * 256 + sr)       * 256 + sw;
    const unsigned short* gA1 = A  + (size_t)(bm * 256 + sr + 64)  * 256 + sw;
    const unsigned short* gA2 = A  + (size_t)(bm * 256 + sr + 128) * 256 + sw;
    const unsigned short* gA3 = A  + (size_t)(bm * 256 + sr + 192) * 256 + sw;
    const unsigned short* gB0 = BT + (size_t)(sr)      * 256 + sw;
    const unsigned short* gB1 = BT + (size_t)(sr + 64) * 256 + sw;

    char* AsB = (char*)As;
    char* BsB = (char*)Bs;
    const int woff = w * 1024;

    f32x4 acc[8][4] = {};

    for (int k0 = 0; k0 < 256; k0 += 32) {
        __syncthreads();
        g2lds16(gA0 + k0, AsB + woff);
        g2lds16(gA1 + k0, AsB + 4096  + woff);
        g2lds16(gA2 + k0, AsB + 8192  + woff);
        g2lds16(gA3 + k0, AsB + 12288 + woff);
        g2lds16(gB0 + k0, BsB + woff);
        g2lds16(gB1 + k0, BsB + 4096 + woff);
        __syncthreads();

        bf16x8 af[8], bfr[4];
#pragma unroll
        for (int mt = 0; mt < 8; ++mt)
            af[mt] = *(const bf16x8*)&As[(wr * 128 + mt * 16 + r16) * 32 + qx];
#pragma unroll
        for (int nt = 0; nt < 4; ++nt)
            bfr[nt] = *(const bf16x8*)&Bs[(wc * 64 + nt * 16 + r16) * 32 + qx];
#pragma unroll
        for (int mt = 0; mt < 8; ++mt)
#pragma unroll
            for (int nt = 0; nt < 4; ++nt)
                acc[mt][nt] = __builtin_amdgcn_mfma_f32_16x16x32_bf16(
                    af[mt], bfr[nt], acc[mt][nt], 0, 0, 0);
    }

    const int mbase = bm * 256 + wr * 128 + quad * 4;
    const int nbase = bn * 128 + wc * 64 + r16;   // global col in 0..639
#pragma unroll
    for (int mt = 0; mt < 8; ++mt) {
#pragma unroll
        for (int nt = 0; nt < 4; ++nt) {
            const int col = nbase + nt * 16;
#pragma unroll
            for (int r = 0; r < 4; ++r) {
                const int row = mbase + mt * 16 + r;
                const float v = acc[mt][nt][r];
                if (bn < 2) {
                    // value, head-major: [b][h][pos][32ch]
                    const int b = (row >= Sn) ? 1 : 0;
                    const int srow = row - b * Sn;
                    const int h = col >> 5, ch = col & 31;
                    valb[(((size_t)b * 8 + h) * Sn + srow) * 32 + ch] =
                        f2bf(v + b_val[col]);
                } else if (bn < 4) {
                    const int c2 = col - 256;
                    const int c = c2 & 1;
                    const int l = (c2 >> 3) & 3;
                    const float invn = 1.f / (float)(128 >> l);
                    const float rp = refpts[(size_t)row * 8 + l * 2 + c];
                    locf[(size_t)row * 256 + c2] = rp + (v + b_off[c2]) * invn;
                } else {
                    const int c2 = col - 512;   // 0..127
                    float x = v + b_attn[c2];
                    float mx = x;
                    mx = fmaxf(mx, __shfl_xor(mx, 1));
                    mx = fmaxf(mx, __shfl_xor(mx, 2));
                    mx = fmaxf(mx, __shfl_xor(mx, 4));
                    mx = fmaxf(mx, __shfl_xor(mx, 8));
                    float e = __expf(x - mx);
                    float s = e;
                    s += __shfl_xor(s, 1);
                    s += __shfl_xor(s, 2);
                    s += __shfl_xor(s, 4);
                    s += __shfl_xor(s, 8);
                    attnf[(size_t)row * 128 + c2] = e / s;
                }
            }
        }
    }
}

// ---------------- ffn1 GEMM: 256x128 tiles, relu -> bf16 ----------------
__global__ __launch_bounds__(256)
void gemm_ffn1(const unsigned short* __restrict__ A,
               const unsigned short* __restrict__ BT,
               const float* __restrict__ bias,
               unsigned short* __restrict__ outp)
{
    __shared__ __align__(16) unsigned short As[256 * 32];   // 16 KB
    __shared__ __align__(16) unsigned short Bs[128 * 32];   // 8 KB

    const int tid  = threadIdx.x;
    const int lane = tid & 63;
    const int w    = tid >> 6;
    const int quad = lane >> 4;
    const int r16  = lane & 15;
    const int wr   = w >> 1, wc = w & 1;
    const int bm   = blockIdx.y, bn = blockIdx.x;

    const int sr = tid >> 2;
    const int sw = (((tid & 3) ^ ((tid >> 3) & 3)) << 3);
    const int qx = ((quad ^ ((r16 >> 1) & 3)) << 3);

    const unsigned short* gA0 = A  + (size_t)(bm * 256 + sr)       * 256 + sw;
    const unsigned short* gA1 = A  + (size_t)(bm * 256 + sr + 64)  * 256 + sw;
    const unsigned short* gA2 = A  + (size_t)(bm * 256 + sr + 128) * 256 + sw;
    const unsigned short* gA3 = A  + (size_t)(bm * 256 + sr + 192) * 256 + sw;
    const unsigned short* gB0 = BT + (size_t)(bn * 128 + sr)      * 256 + sw;
    const unsigned short* gB1 = BT + (size_t)(bn * 128 + sr + 64) * 256 + sw;

    char* AsB = (char*)As;
    char* BsB = (char*)Bs;
    const int woff = w * 1024;

    f32x4 acc[8][4] = {};

    for (int k0 = 0; k0 < 256; k0 += 32) {
        __syncthreads();
        g2lds16(gA0 + k0, AsB + woff);
        g2lds16(gA1 + k0, AsB + 4096  + woff);
        g2lds16(gA2 + k0, AsB + 8192  + woff);
        g2lds16(gA3 + k0, AsB + 12288 + woff);
        g2lds16(gB0 + k0, BsB + woff);
        g2lds16(gB1 + k0, BsB + 4096 + woff);
        __syncthreads();

        bf16x8 af[8], bfr[4];
#pragma unroll
        for (int mt = 0; mt < 8; ++mt)
            af[mt] = *(const bf16x8*)&As[(wr * 128 + mt * 16 + r16) * 32 + qx];
#pragma unroll
        for (int nt = 0; nt < 4; ++nt)
            bfr[nt] = *(const bf16x8*)&Bs[(wc * 64 + nt * 16 + r16) * 32 + qx];
#pragma unroll
        for (int mt = 0; mt < 8; ++mt)
#pragma unroll
            for (int nt = 0; nt < 4; ++nt)
                acc[mt][nt] = __builtin_amdgcn_mfma_f32_16x16x32_bf16(
                    af[mt], bfr[nt], acc[mt][nt], 0, 0, 0);
    }

    const int mbase = bm * 256 + wr * 128 + quad * 4;
    const int nbase = bn * 128 + wc * 64 + r16;
#pragma unroll
    for (int mt = 0; mt < 8; ++mt) {
#pragma unroll
        for (int nt = 0; nt < 4; ++nt) {
            const int col = nbase + nt * 16;
#pragma unroll
            for (int r = 0; r < 4; ++r) {
                const int row = mbase + mt * 16 + r;
                float t = acc[mt][nt][r] + bias[col];
                outp[(size_t)row * 1024 + col] = f2bf(t > 0.f ? t : 0.f);
            }
        }
    }
}

// ---------------- GEMM + residual + LayerNorm fused (64x256 tile, full row in block) ----
// MODE 0: out-proj: t = acc + bias + resid(src);  y = LN1(t); out=y fp32, xb=bf16(y)
// MODE 1: ffn2:     t = acc + bias + resid(x=d_out); y = LN2(t); out=y fp32
// (R1-measured single-buffer structure + swizzle)
template<int MODE, int K>
__global__ __launch_bounds__(256)
void gemm_ln(const unsigned short* __restrict__ A,
             const unsigned short* __restrict__ BT,
             const float* __restrict__ bias,
             const float* __restrict__ gamma, const float* __restrict__ beta,
             const float* resid,
             float* out, unsigned short* __restrict__ xb)
{
    __shared__ __align__(16) unsigned short As[64 * 32];    // 4 KB
    __shared__ __align__(16) unsigned short Bs[256 * 32];   // 16 KB
    __shared__ float red[2][64][2];

    const int tid  = threadIdx.x;
    const int lane = tid & 63;
    const int w    = tid >> 6;
    const int quad = lane >> 4;
    const int r16  = lane & 15;
    const int wr   = w >> 1, wc = w & 1;   // wave tile 32 rows x 128 cols
    const int bm   = blockIdx.x;

    const int sr = tid >> 2;          // 0..63
    const int sw = (((tid & 3) ^ ((tid >> 3) & 3)) << 3);
    const int qx = ((quad ^ ((r16 >> 1) & 3)) << 3);

    const unsigned short* gA  = A  + (size_t)(bm * 64 + sr) * K + sw;
    const unsigned short* gB0 = BT + (size_t)(sr)       * K + sw;
    const unsigned short* gB1 = BT + (size_t)(sr + 64)  * K + sw;
    const unsigned short* gB2 = BT + (size_t)(sr + 128) * K + sw;
    const unsigned short* gB3 = BT + (size_t)(sr + 192) * K + sw;

    char* AsB = (char*)As;
    char* BsB = (char*)Bs;
    const int woff = w * 1024;

    f32x4 acc[2][8] = {};

    for (int k0 = 0; k0 < K; k0 += 32) {
        __syncthreads();
        g2lds16(gA  + k0, AsB + woff);
        g2lds16(gB0 + k0, BsB + woff);
        g2lds16(gB1 + k0, BsB + 4096  + woff);
        g2lds16(gB2 + k0, BsB + 8192  + woff);
        g2lds16(gB3 + k0, BsB + 12288 + woff);
        __syncthreads();

        bf16x8 af[2], bfr[8];
#pragma unroll
        for (int mt = 0; mt < 2; ++mt)
            af[mt] = *(const bf16x8*)&As[(wr * 32 + mt * 16 + r16) * 32 + qx];
#pragma unroll
        for (int nt = 0; nt < 8; ++nt)
            bfr[nt] = *(const bf16x8*)&Bs[(wc * 128 + nt * 16 + r16) * 32 + qx];
#pragma unroll
        for (int mt = 0; mt < 2; ++mt)
#pragma unroll
            for (int nt = 0; nt < 8; ++nt)
                acc[mt][nt] = __builtin_amdgcn_mfma_f32_16x16x32_bf16(
                    af[mt], bfr[nt], acc[mt][nt], 0, 0, 0);
    }

    // t = acc + bias + resid  (in place)
    const int rl_base = wr * 32 + quad * 4;
    const int cbase   = wc * 128 + r16;
#pragma unroll
    for (int mt = 0; mt < 2; ++mt)
#pragma unroll
        for (int nt = 0; nt < 8; ++nt) {
            const int col = cbase + nt * 16;
#pragma unroll
            for (int r = 0; r < 4; ++r) {
                const int rowl = rl_base + mt * 16 + r;
                const size_t gix = (size_t)(bm * 64 + rowl) * 256 + col;
                acc[mt][nt][r] += bias[col] + resid[gix];
            }
        }

    // per-row sums over this wave's 128 cols, then cross-wave via LDS
#pragma unroll
    for (int mt = 0; mt < 2; ++mt)
#pragma unroll
        for (int r = 0; r < 4; ++r) {
            float s = 0.f, s2 = 0.f;
#pragma unroll
            for (int nt = 0; nt < 8; ++nt) {
                const float v = acc[mt][nt][r];
                s += v; s2 += v * v;
            }
            s  += __shfl_xor(s, 1);  s2 += __shfl_xor(s2, 1);
            s  += __shfl_xor(s, 2);  s2 += __shfl_xor(s2, 2);
            s  += __shfl_xor(s, 4);  s2 += __shfl_xor(s2, 4);
            s  += __shfl_xor(s, 8);  s2 += __shfl_xor(s2, 8);
            if (r16 == 0) {
                const int rowl = rl_base + mt * 16 + r;
                red[wc][rowl][0] = s;
                red[wc][rowl][1] = s2;
            }
        }
    __syncthreads();

#pragma unroll
    for (int mt = 0; mt < 2; ++mt)
#pragma unroll
        for (int r = 0; r < 4; ++r) {
            const int rowl = rl_base + mt * 16 + r;
            const float ts  = red[0][rowl][0] + red[1][rowl][0];
            const float ts2 = red[0][rowl][1] + red[1][rowl][1];
            const float mu  = ts * (1.f / 256.f);
            const float var = ts2 * (1.f / 256.f) - mu * mu;
            const float inv = rsqrtf(var + 1e-5f);
#pragma unroll
            for (int nt = 0; nt < 8; ++nt) {
                const int col = cbase + nt * 16;
                const size_t gix = (size_t)(bm * 64 + rowl) * 256 + col;
                const float y = (acc[mt][nt][r] - mu) * inv * gamma[col] + beta[col];
                out[gix] = y;
                if constexpr (MODE == 0) xb[gix] = f2bf(y);
            }
        }
}

// ---------------- deformable sampling, v5: head-partitioned (XCD-local value) ----------
__global__ __launch_bounds__(256)
void deform_sample(const unsigned short* __restrict__ val,   // (B,8,Sn,32) bf16
                   const float* __restrict__ loc,            // (BS,256) fp32  (h,l,p,c)
                   const float* __restrict__ attn,           // (BS,128) fp32  (h,l,p)
                   unsigned short* __restrict__ accb)        // (BS,256) bf16
{
    __shared__ float s_loc[64][33];
    __shared__ float s_attn[64][17];

    const int tid   = threadIdx.x;
    const int xcd   = blockIdx.x & 7;       // round-robin XCD id
    const int chunk = blockIdx.x >> 3;      // 0..679
    const int b     = chunk & 1;
    const int h     = xcd;                  // one head per XCD
    const int tc    = chunk >> 1;           // 0..339
    const int tbase = b * Sn + tc * 64;

    for (int i = tid; i < 64 * 32; i += 256) {
        const int tok = i >> 5, k = i & 31;
        s_loc[tok][k] = loc[(size_t)(tbase + tok) * 256 + h * 32 + k];
    }
    for (int i = tid; i < 64 * 16; i += 256) {
        const int tok = i >> 4, k = i & 15;
        s_attn[tok][k] = attn[(size_t)(tbase + tok) * 128 + h * 16 + k];
    }
    __syncthreads();

    const int c4 = tid & 3;                 // channel group (8 ch = 16 B)
    const int it = tid >> 2;                // token in block, 0..63
    const int t  = tbase + it;

    const int sz[4] = {128, 64, 32, 16};
    const int st[4] = {0, 16384, 20480, 21504};

    const unsigned short* valh = val + ((size_t)(b * 8 + h) * Sn) * 32 + c4 * 8;

    f32x2 acc0 = {0.f, 0.f}, acc1 = {0.f, 0.f}, acc2a = {0.f, 0.f}, acc3 = {0.f, 0.f};

#pragma unroll
    for (int l = 0; l < 4; ++l) {
        const int W = sz[l];
        const float Wf = (float)W;
        const unsigned short* lptr = valh + (size_t)st[l] * 32;

        const int pl = l * 4 + c4;
        const float aw = s_attn[it][pl];
        const float fx = s_loc[it][pl * 2]     * Wf - 0.5f;
        const float fy = s_loc[it][pl * 2 + 1] * Wf - 0.5f;
        const float xf = floorf(fx), yf = floorf(fy);
        const float wx = fx - xf,  wy = fy - yf;
        const int x0 = (int)xf, y0 = (int)yf;
        const int x1 = x0 + 1,  y1 = y0 + 1;
        const float vx0 = (x0 >= 0 && x0 < W) ? 1.f : 0.f;
        const float vx1 = (x1 >= 0 && x1 < W) ? 1.f : 0.f;
        const float vy0 = (y0 >= 0 && y0 < W) ? 1.f : 0.f;
        const float vy1 = (y1 >= 0 && y1 < W) ? 1.f : 0.f;
        const int x0c = min(max(x0, 0), W - 1);
        const int x1c = min(max(x1, 0), W - 1);
        const int y0c = min(max(y0, 0), W - 1);
        const int y1c = min(max(y1, 0), W - 1);

        const float w00 = aw * (1.f - wx) * (1.f - wy) * vx0 * vy0;
        const float w01 = aw * wx         * (1.f - wy) * vx1 * vy0;
        const float w10 = aw * (1.f - wx) * wy         * vx0 * vy1;
        const float w11 = aw * wx         * wy         * vx1 * vy1;
        const int a00 = y0c * W + x0c;
        const int a01 = y0c * W + x1c;
        const int a10 = y1c * W + x0c;
        const int a11 = y1c * W + x1c;

#pragma unroll
        for (int p = 0; p < 4; ++p) {
            const float u00 = __shfl(w00, p, 4);
            const float u01 = __shfl(w01, p, 4);
            const float u10 = __shfl(w10, p, 4);
            const float u11 = __shfl(w11, p, 4);
            const int   e00 = __shfl(a00, p, 4);
            const int   e01 = __shfl(a01, p, 4);
            const int   e10 = __shfl(a10, p, 4);
            const int   e11 = __shfl(a11, p, 4);

            const uint4 q00 = *(const uint4*)(lptr + (size_t)e00 * 32);
            const uint4 q01 = *(const uint4*)(lptr + (size_t)e01 * 32);
            const uint4 q10 = *(const uint4*)(lptr + (size_t)e10 * 32);
            const uint4 q11 = *(const uint4*)(lptr + (size_t)e11 * 32);

            f32x2 wv;
            wv.x = u00; wv.y = u00;
            acc0 += wv * cvt2(q00.x); acc1 += wv * cvt2(q00.y);
            acc2a += wv * cvt2(q00.z); acc3 += wv * cvt2(q00.w);
            wv.x = u01; wv.y = u01;
            acc0 += wv * cvt2(q01.x); acc1 += wv * cvt2(q01.y);
            acc2a += wv * cvt2(q01.z); acc3 += wv * cvt2(q01.w);
            wv.x = u10; wv.y = u10;
            acc0 += wv * cvt2(q10.x); acc1 += wv * cvt2(q10.y);
            acc2a += wv * cvt2(q10.z); acc3 += wv * cvt2(q10.w);
            wv.x = u11; wv.y = u11;
            acc0 += wv * cvt2(q11.x); acc1 += wv * cvt2(q11.y);
            acc2a += wv * cvt2(q11.z); acc3 += wv * cvt2(q11.w);
        }
    }

    uint4 o;
    o.x = (unsigned int)f2bf(acc0.x) | ((unsigned int)f2bf(acc0.y) << 16);
    o.y = (unsigned int)f2bf(acc1.x) | ((unsigned int)f2bf(acc1.y) << 16);
    o.z = (unsigned int)f2bf(acc2a.x) | ((unsigned int)f2bf(acc2a.y) << 16);
    o.w = (unsigned int)f2bf(acc3.x) | ((unsigned int)f2bf(acc3.y) << 16);
    *(uint4*)(accb + (size_t)t * 256 + h * 32 + c4 * 8) = o;
}

// ---------------- launch ----------------
extern "C" void kernel_launch(void* const* d_in, const int* in_sizes, int n_in,
                              void* d_out, int out_size, void* d_ws, size_t ws_size,
                              hipStream_t stream) {
    const float* src    = (const float*)d_in[0];
    const float* pos    = (const float*)d_in[1];
    const float* refpts = (const float*)d_in[2];
    const float* W_off  = (const float*)d_in[5];
    const float* b_off  = (const float*)d_in[6];
    const float* W_attn = (const float*)d_in[7];
    const float* b_attn = (const float*)d_in[8];
    const float* W_val  = (const float*)d_in[9];
    const float* b_val  = (const float*)d_in[10];
    const float* W_out  = (const float*)d_in[11];
    const float* b_out  = (const float*)d_in[12];
    const float* W_ffn1 = (const float*)d_in[13];
    const float* b_ffn1 = (const float*)d_in[14];
    const float* W_ffn2 = (const float*)d_in[15];
    const float* b_ffn2 = (const float*)d_in[16];
    const float* ln1_g  = (const float*)d_in[17];
    const float* ln1_b  = (const float*)d_in[18];
    const float* ln2_g  = (const float*)d_in[19];
    const float* ln2_b  = (const float*)d_in[20];

    char* ws = (char*)d_ws;

    unsigned short* wT      = (unsigned short*)ws;
    unsigned short* WprojT  = wT + 0;        // 640x256
    unsigned short* WoutT   = wT + 163840;   // 256x256
    unsigned short* Wffn1T  = wT + 229376;   // 1024x256
    unsigned short* Wffn2T  = wT + 491520;   // 256x1024

    constexpr size_t SZ_TOK_BF = (size_t)BS * 256 * 2;
    constexpr size_t SZ_TOK_F  = (size_t)BS * 256 * 4;
    const size_t o = 2u * 1024 * 1024;
    unsigned short* srcb  = (unsigned short*)(ws + o);                         // later: x_bf16
    unsigned short* qb    = (unsigned short*)(ws + o + SZ_TOK_BF);             // later: acc_bf16
    unsigned short* valb  = (unsigned short*)(ws + o + 2 * SZ_TOK_BF);         // later: h_bf16 overlay
    float*          locf  = (float*)(ws + o + 3 * SZ_TOK_BF);
    float*          attnf = (float*)(ws + o + 3 * SZ_TOK_BF + SZ_TOK_F);
    unsigned short* hb    = valb;   // ffn hidden overlays value+loc+attn
    unsigned short* xb    = srcb;
    unsigned short* accb  = qb;

    float* out = (float*)d_out;

    // 1) weights
    transpose_all<<<(753664 + 255) / 256, 256, 0, stream>>>(
        W_val, W_off, W_attn, W_out, W_ffn1, W_ffn2, wT);

    // 2) activations prep (float4-vectorized)
    prep_q<<<2048, 256, 0, stream>>>(src, pos, srcb, qb, BS * 256);

    // 3) fused projections: value(head-major) + loc + attn(softmax), 256-row tiles
    gemm_proj<<<dim3(5, BS / 256), 256, 0, stream>>>(
        srcb, qb, WprojT, b_val, b_off, b_attn, refpts, valb, locf, attnf);

    // 4) deformable bilinear sampling + weighted sum (head-partitioned per XCD)
    deform_sample<<<BS / 8, 256, 0, stream>>>(valb, locf, attnf, accb);

    // 5) out-proj + residual(src) + LN1 -> out fp32 + xb bf16
    gemm_ln<0, 256><<<BS / 64, 256, 0, stream>>>(
        accb, WoutT, b_out, ln1_g, ln1_b, src, out, xb);

    // 6) FFN1 + relu -> bf16, 256-row tiles
    gemm_ffn1<<<dim3(8, BS / 256), 256, 0, stream>>>(xb, Wffn1T, b_ffn1, hb);

    // 7) FFN2 + residual(x=out) + LN2 -> out fp32 (final)
    gemm_ln<1, 1024><<<BS / 64, 256, 0, stream>>>(
        hb, Wffn2T, b_ffn2, ln2_g, ln2_b, out, out, nullptr);
}

// Round 6
// 561.331 us; speedup vs baseline: 1.5344x; 1.5344x over previous
//
#include <hip/hip_runtime.h>
#include <stdint.h>
#include <stddef.h>

// ---------------- problem constants ----------------
constexpr int Dm  = 256;
constexpr int NH  = 8;
constexpr int NL  = 4;
constexpr int NP  = 4;
constexpr int DFF = 1024;
constexpr int Bb  = 2;
constexpr int Sn  = 21760;            // 128*128 + 64*64 + 32*32 + 16*16
constexpr int BS  = Bb * Sn;          // 43520  (= 340 * 128 exactly)
constexpr int DH  = Dm / NH;          // 32

// ---------------- small helpers ----------------
__device__ __forceinline__ unsigned short f2bf(float f) {
    union { float f; unsigned int u; } v; v.f = f;
    unsigned int u = v.u;
    unsigned int r = u + 0x7FFFu + ((u >> 16) & 1u);   // round-nearest-even
    return (unsigned short)(r >> 16);
}

typedef float  f32x4  __attribute__((ext_vector_type(4)));
typedef float  f32x2  __attribute__((ext_vector_type(2)));
typedef __bf16 bf16x8 __attribute__((ext_vector_type(8)));

// unpack 2 bf16 (packed in u32) -> float2
__device__ __forceinline__ f32x2 cvt2(unsigned int u) {
    union { unsigned int u; float f; } lo, hi;
    lo.u = u << 16; hi.u = u & 0xFFFF0000u;
    f32x2 r; r.x = lo.f; r.y = hi.f; return r;
}

// address-space helpers for global_load_lds
typedef const __attribute__((address_space(1))) unsigned int GU;
typedef __attribute__((address_space(3))) unsigned int LU;
__device__ __forceinline__ void g2lds16(const void* g, void* l) {
    __builtin_amdgcn_global_load_lds((GU*)g, (LU*)l, 16, 0, 0);
}

// ---------------- all weights: convert + transpose in ONE kernel ----------------
// wT element layout (all N-major, [n][k]):
//   WprojT @0       : 640 x 256  (cols 0-255 W_val, 256-511 W_off, 512-639 W_attn)
//   WoutT  @163840  : 256 x 256
//   Wffn1T @229376  : 1024 x 256
//   Wffn2T @491520  : 256 x 1024
__global__ void transpose_all(const float* __restrict__ W_val, const float* __restrict__ W_off,
                              const float* __restrict__ W_attn, const float* __restrict__ W_out,
                              const float* __restrict__ W_ffn1, const float* __restrict__ W_ffn2,
                              unsigned short* __restrict__ wT) {
    int i = blockIdx.x * 256 + threadIdx.x;
    float v;
    if (i < 163840) {                       // proj block
        int n = i >> 8, k = i & 255;
        if      (n < 256) v = W_val[(size_t)k * 256 + n];
        else if (n < 512) v = W_off[(size_t)k * 256 + (n - 256)];
        else              v = W_attn[(size_t)k * 128 + (n - 512)];
    } else if (i < 229376) {
        int j = i - 163840, n = j >> 8, k = j & 255;
        v = W_out[(size_t)k * 256 + n];
    } else if (i < 491520) {
        int j = i - 229376, n = j >> 8, k = j & 255;
        v = W_ffn1[(size_t)k * 1024 + n];
    } else if (i < 753664) {
        int j = i - 491520, n = j >> 10, k = j & 1023;
        v = W_ffn2[(size_t)k * 256 + n];
    } else return;
    wT[i] = f2bf(v);
}

// ---------------- q = src+pos (bf16), src (bf16), float4-vectorized ----------------
__global__ void prep_q(const float* __restrict__ src, const float* __restrict__ pos,
                       unsigned short* __restrict__ srcb, unsigned short* __restrict__ qb,
                       int ntot) {
    for (int i = (blockIdx.x * blockDim.x + threadIdx.x) * 4; i < ntot;
         i += gridDim.x * blockDim.x * 4) {
        const float4 s = *(const float4*)&src[i];
        const float4 p = *(const float4*)&pos[i];
        ushort4 sb, qb4;
        sb.x = f2bf(s.x); sb.y = f2bf(s.y); sb.z = f2bf(s.z); sb.w = f2bf(s.w);
        qb4.x = f2bf(s.x + p.x); qb4.y = f2bf(s.y + p.y);
        qb4.z = f2bf(s.z + p.z); qb4.w = f2bf(s.w + p.w);
        *(ushort4*)&srcb[i] = sb;
        *(ushort4*)&qb[i]   = qb4;
    }
}

// ---------------- fused projection GEMM: value + offsets + attn(softmax) ----------------
// v6: persistent-B. B slab (128x256, 64 KB) staged ONCE per block as 8 copies of the
// proven per-step layout (reads byte-identical to R1). Block then loops 4 M-tiles,
// staging only A (8 KB/step) -> staged bytes 218 -> 136 MB. acc[4][4] as R1 (no spill).
// Grid (5, 85). LDS 72 KB -> 2 blocks/CU.
__global__ __launch_bounds__(256)
void gemm_proj(const unsigned short* __restrict__ srcb,
               const unsigned short* __restrict__ qb,
               const unsigned short* __restrict__ WprojT,
               const float* __restrict__ b_val, const float* __restrict__ b_off,
               const float* __restrict__ b_attn, const float* __restrict__ refpts,
               unsigned short* __restrict__ valb, float* __restrict__ locf,
               float* __restrict__ attnf)
{
    __shared__ __align__(16) unsigned short As[128 * 32];        // 8 KB
    __shared__ __align__(16) unsigned short Bs[8 * 128 * 32];    // 64 KB (8 K-slabs)

    const int tid  = threadIdx.x;
    const int lane = tid & 63;
    const int w    = tid >> 6;
    const int quad = lane >> 4;
    const int r16  = lane & 15;
    const int wr   = w >> 1, wc = w & 1;
    const int bn   = blockIdx.x;
    const int bm0  = blockIdx.y * 4;

    const unsigned short* A  = (bn < 2) ? srcb : qb;
    const unsigned short* BT = WprojT + (size_t)bn * 128 * 256;

    const int sr = tid >> 2;
    const int sw = (((tid & 3) ^ ((tid >> 3) & 3)) << 3);
    const int qx = ((quad ^ ((r16 >> 1) & 3)) << 3);

    const unsigned short* gB0 = BT + (size_t)(sr)      * 256 + sw;
    const unsigned short* gB1 = BT + (size_t)(sr + 64) * 256 + sw;

    char* AsB = (char*)As;
    char* BsB = (char*)Bs;
    const int woff = w * 1024;

    // stage the whole B slab once: slab k = exact per-step layout of K-step k
#pragma unroll
    for (int k = 0; k < 8; ++k) {
        g2lds16(gB0 + k * 32, BsB + k * 8192 + woff);
        g2lds16(gB1 + k * 32, BsB + k * 8192 + 4096 + woff);
    }
    __syncthreads();

    for (int t = 0; t < 4; ++t) {
        const int bm = bm0 + t;
        const unsigned short* gA0 = A + (size_t)(bm * 128 + sr)      * 256 + sw;
        const unsigned short* gA1 = A + (size_t)(bm * 128 + sr + 64) * 256 + sw;

        f32x4 acc[4][4] = {};

        for (int k0 = 0; k0 < 256; k0 += 32) {
            __syncthreads();
            g2lds16(gA0 + k0, AsB + woff);
            g2lds16(gA1 + k0, AsB + 4096 + woff);
            __syncthreads();

            bf16x8 af[4], bfr[4];
#pragma unroll
            for (int mt = 0; mt < 4; ++mt)
                af[mt] = *(const bf16x8*)&As[(wr * 64 + mt * 16 + r16) * 32 + qx];
#pragma unroll
            for (int nt = 0; nt < 4; ++nt)
                bfr[nt] = *(const bf16x8*)&Bs[(k0 << 7) + (wc * 64 + nt * 16 + r16) * 32 + qx];
#pragma unroll
            for (int mt = 0; mt < 4; ++mt)
#pragma unroll
                for (int nt = 0; nt < 4; ++nt)
                    acc[mt][nt] = __builtin_amdgcn_mfma_f32_16x16x32_bf16(
                        af[mt], bfr[nt], acc[mt][nt], 0, 0, 0);
        }

        const int mbase = bm * 128 + wr * 64 + quad * 4;
        const int nbase = bn * 128 + wc * 64 + r16;   // global col in 0..639
#pragma unroll
        for (int mt = 0; mt < 4; ++mt) {
#pragma unroll
            for (int nt = 0; nt < 4; ++nt) {
                const int col = nbase + nt * 16;
#pragma unroll
                for (int r = 0; r < 4; ++r) {
                    const int row = mbase + mt * 16 + r;
                    const float v = acc[mt][nt][r];
                    if (bn < 2) {
                        // value, head-major: [b][h][pos][32ch]
                        const int b = (row >= Sn) ? 1 : 0;
                        const int srow = row - b * Sn;
                        const int h = col >> 5, ch = col & 31;
                        valb[(((size_t)b * 8 + h) * Sn + srow) * 32 + ch] =
                            f2bf(v + b_val[col]);
                    } else if (bn < 4) {
                        const int c2 = col - 256;
                        const int c = c2 & 1;
                        const int l = (c2 >> 3) & 3;
                        const float invn = 1.f / (float)(128 >> l);
                        const float rp = refpts[(size_t)row * 8 + l * 2 + c];
                        locf[(size_t)row * 256 + c2] = rp + (v + b_off[c2]) * invn;
                    } else {
                        const int c2 = col - 512;   // 0..127
                        float x = v + b_attn[c2];
                        float mx = x;
                        mx = fmaxf(mx, __shfl_xor(mx, 1));
                        mx = fmaxf(mx, __shfl_xor(mx, 2));
                        mx = fmaxf(mx, __shfl_xor(mx, 4));
                        mx = fmaxf(mx, __shfl_xor(mx, 8));
                        float e = __expf(x - mx);
                        float s = e;
                        s += __shfl_xor(s, 1);
                        s += __shfl_xor(s, 2);
                        s += __shfl_xor(s, 4);
                        s += __shfl_xor(s, 8);
                        attnf[(size_t)row * 128 + c2] = e / s;
                    }
                }
            }
        }
    }
}

// ---------------- ffn1 GEMM: persistent-B, 4 M-tiles per block, relu -> bf16 ----------
__global__ __launch_bounds__(256)
void gemm_ffn1(const unsigned short* __restrict__ A,
               const unsigned short* __restrict__ BT,
               const float* __restrict__ bias,
               unsigned short* __restrict__ outp)
{
    __shared__ __align__(16) unsigned short As[128 * 32];        // 8 KB
    __shared__ __align__(16) unsigned short Bs[8 * 128 * 32];    // 64 KB

    const int tid  = threadIdx.x;
    const int lane = tid & 63;
    const int w    = tid >> 6;
    const int quad = lane >> 4;
    const int r16  = lane & 15;
    const int wr   = w >> 1, wc = w & 1;
    const int bn   = blockIdx.x;
    const int bm0  = blockIdx.y * 4;

    const int sr = tid >> 2;
    const int sw = (((tid & 3) ^ ((tid >> 3) & 3)) << 3);
    const int qx = ((quad ^ ((r16 >> 1) & 3)) << 3);

    const unsigned short* gB0 = BT + (size_t)(bn * 128 + sr)      * 256 + sw;
    const unsigned short* gB1 = BT + (size_t)(bn * 128 + sr + 64) * 256 + sw;

    char* AsB = (char*)As;
    char* BsB = (char*)Bs;
    const int woff = w * 1024;

#pragma unroll
    for (int k = 0; k < 8; ++k) {
        g2lds16(gB0 + k * 32, BsB + k * 8192 + woff);
        g2lds16(gB1 + k * 32, BsB + k * 8192 + 4096 + woff);
    }
    __syncthreads();

    for (int t = 0; t < 4; ++t) {
        const int bm = bm0 + t;
        const unsigned short* gA0 = A + (size_t)(bm * 128 + sr)      * 256 + sw;
        const unsigned short* gA1 = A + (size_t)(bm * 128 + sr + 64) * 256 + sw;

        f32x4 acc[4][4] = {};

        for (int k0 = 0; k0 < 256; k0 += 32) {
            __syncthreads();
            g2lds16(gA0 + k0, AsB + woff);
            g2lds16(gA1 + k0, AsB + 4096 + woff);
            __syncthreads();

            bf16x8 af[4], bfr[4];
#pragma unroll
            for (int mt = 0; mt < 4; ++mt)
                af[mt] = *(const bf16x8*)&As[(wr * 64 + mt * 16 + r16) * 32 + qx];
#pragma unroll
            for (int nt = 0; nt < 4; ++nt)
                bfr[nt] = *(const bf16x8*)&Bs[(k0 << 7) + (wc * 64 + nt * 16 + r16) * 32 + qx];
#pragma unroll
            for (int mt = 0; mt < 4; ++mt)
#pragma unroll
                for (int nt = 0; nt < 4; ++nt)
                    acc[mt][nt] = __builtin_amdgcn_mfma_f32_16x16x32_bf16(
                        af[mt], bfr[nt], acc[mt][nt], 0, 0, 0);
        }

        const int mbase = bm * 128 + wr * 64 + quad * 4;
        const int nbase = bn * 128 + wc * 64 + r16;
#pragma unroll
        for (int mt = 0; mt < 4; ++mt) {
#pragma unroll
            for (int nt = 0; nt < 4; ++nt) {
                const int col = nbase + nt * 16;
#pragma unroll
                for (int r = 0; r < 4; ++r) {
                    const int row = mbase + mt * 16 + r;
                    float tv = acc[mt][nt][r] + bias[col];
                    outp[(size_t)row * 1024 + col] = f2bf(tv > 0.f ? tv : 0.f);
                }
            }
        }
    }
}

// ---------------- GEMM + residual + LayerNorm fused (128x256 tile, 512 threads) --------
// MODE 0: out-proj: t = acc + bias + resid(src);  y = LN1(t); out=y fp32, xb=bf16(y)
// MODE 1: ffn2:     t = acc + bias + resid(x=d_out); y = LN2(t); out=y fp32
// v4: M=128 with 8 waves (4 row-groups x 2 col-groups). Same acc[2][8] per thread,
// same staging algebra; B-tile amortized over 2x rows -> staged bytes x0.6.
template<int MODE, int K>
__global__ __launch_bounds__(512)
void gemm_ln(const unsigned short* __restrict__ A,
             const unsigned short* __restrict__ BT,
             const float* __restrict__ bias,
             const float* __restrict__ gamma, const float* __restrict__ beta,
             const float* resid,
             float* out, unsigned short* __restrict__ xb)
{
    __shared__ __align__(16) unsigned short As[128 * 32];   // 8 KB
    __shared__ __align__(16) unsigned short Bs[256 * 32];   // 16 KB
    __shared__ float red[2][128][2];                        // 2 KB

    const int tid  = threadIdx.x;
    const int lane = tid & 63;
    const int w    = tid >> 6;          // 0..7
    const int quad = lane >> 4;
    const int r16  = lane & 15;
    const int wr   = w >> 1, wc = w & 1;   // wave tile: 32 rows x 128 cols
    const int bm   = blockIdx.x;

    const int sr = tid >> 2;          // 0..127
    const int sw = (((tid & 3) ^ ((tid >> 3) & 3)) << 3);
    const int qx = ((quad ^ ((r16 >> 1) & 3)) << 3);

    const unsigned short* gA  = A  + (size_t)(bm * 128 + sr) * K + sw;
    const unsigned short* gB0 = BT + (size_t)(sr)       * K + sw;
    const unsigned short* gB1 = BT + (size_t)(sr + 128) * K + sw;

    char* AsB = (char*)As;
    char* BsB = (char*)Bs;
    const int woff = w * 1024;

    f32x4 acc[2][8] = {};

    for (int k0 = 0; k0 < K; k0 += 32) {
        __syncthreads();
        g2lds16(gA  + k0, AsB + woff);
        g2lds16(gB0 + k0, BsB + woff);
        g2lds16(gB1 + k0, BsB + 8192 + woff);
        __syncthreads();

        bf16x8 af[2], bfr[8];
#pragma unroll
        for (int mt = 0; mt < 2; ++mt)
            af[mt] = *(const bf16x8*)&As[(wr * 32 + mt * 16 + r16) * 32 + qx];
#pragma unroll
        for (int nt = 0; nt < 8; ++nt)
            bfr[nt] = *(const bf16x8*)&Bs[(wc * 128 + nt * 16 + r16) * 32 + qx];
#pragma unroll
        for (int mt = 0; mt < 2; ++mt)
#pragma unroll
            for (int nt = 0; nt < 8; ++nt)
                acc[mt][nt] = __builtin_amdgcn_mfma_f32_16x16x32_bf16(
                    af[mt], bfr[nt], acc[mt][nt], 0, 0, 0);
    }

    // t = acc + bias + resid  (in place)
    const int rl_base = wr * 32 + quad * 4;
    const int cbase   = wc * 128 + r16;
#pragma unroll
    for (int mt = 0; mt < 2; ++mt)
#pragma unroll
        for (int nt = 0; nt < 8; ++nt) {
            const int col = cbase + nt * 16;
#pragma unroll
            for (int r = 0; r < 4; ++r) {
                const int rowl = rl_base + mt * 16 + r;
                const size_t gix = (size_t)(bm * 128 + rowl) * 256 + col;
                acc[mt][nt][r] += bias[col] + resid[gix];
            }
        }

    // per-row sums over this wave's 128 cols, then cross col-group via LDS
#pragma unroll
    for (int mt = 0; mt < 2; ++mt)
#pragma unroll
        for (int r = 0; r < 4; ++r) {
            float s = 0.f, s2 = 0.f;
#pragma unroll
            for (int nt = 0; nt < 8; ++nt) {
                const float v = acc[mt][nt][r];
                s += v; s2 += v * v;
            }
            s  += __shfl_xor(s, 1);  s2 += __shfl_xor(s2, 1);
            s  += __shfl_xor(s, 2);  s2 += __shfl_xor(s2, 2);
            s  += __shfl_xor(s, 4);  s2 += __shfl_xor(s2, 4);
            s  += __shfl_xor(s, 8);  s2 += __shfl_xor(s2, 8);
            if (r16 == 0) {
                const int rowl = rl_base + mt * 16 + r;
                red[wc][rowl][0] = s;
                red[wc][rowl][1] = s2;
            }
        }
    __syncthreads();

#pragma unroll
    for (int mt = 0; mt < 2; ++mt)
#pragma unroll
        for (int r = 0; r < 4; ++r) {
            const int rowl = rl_base + mt * 16 + r;
            const float ts  = red[0][rowl][0] + red[1][rowl][0];
            const float ts2 = red[0][rowl][1] + red[1][rowl][1];
            const float mu  = ts * (1.f / 256.f);
            const float var = ts2 * (1.f / 256.f) - mu * mu;
            const float inv = rsqrtf(var + 1e-5f);
#pragma unroll
            for (int nt = 0; nt < 8; ++nt) {
                const int col = cbase + nt * 16;
                const size_t gix = (size_t)(bm * 128 + rowl) * 256 + col;
                const float y = (acc[mt][nt][r] - mu) * inv * gamma[col] + beta[col];
                out[gix] = y;
                if constexpr (MODE == 0) xb[gix] = f2bf(y);
            }
        }
}

// ---------------- deformable sampling, v5: head-partitioned (XCD-local value) ----------
__global__ __launch_bounds__(256)
void deform_sample(const unsigned short* __restrict__ val,   // (B,8,Sn,32) bf16
                   const float* __restrict__ loc,            // (BS,256) fp32  (h,l,p,c)
                   const float* __restrict__ attn,           // (BS,128) fp32  (h,l,p)
                   unsigned short* __restrict__ accb)        // (BS,256) bf16
{
    __shared__ float s_loc[64][33];
    __shared__ float s_attn[64][17];

    const int tid   = threadIdx.x;
    const int xcd   = blockIdx.x & 7;       // round-robin XCD id
    const int chunk = blockIdx.x >> 3;      // 0..679
    const int b     = chunk & 1;
    const int h     = xcd;                  // one head per XCD
    const int tc    = chunk >> 1;           // 0..339
    const int tbase = b * Sn + tc * 64;

    for (int i = tid; i < 64 * 32; i += 256) {
        const int tok = i >> 5, k = i & 31;
        s_loc[tok][k] = loc[(size_t)(tbase + tok) * 256 + h * 32 + k];
    }
    for (int i = tid; i < 64 * 16; i += 256) {
        const int tok = i >> 4, k = i & 15;
        s_attn[tok][k] = attn[(size_t)(tbase + tok) * 128 + h * 16 + k];
    }
    __syncthreads();

    const int c4 = tid & 3;                 // channel group (8 ch = 16 B)
    const int it = tid >> 2;                // token in block, 0..63
    const int t  = tbase + it;

    const int sz[4] = {128, 64, 32, 16};
    const int st[4] = {0, 16384, 20480, 21504};

    const unsigned short* valh = val + ((size_t)(b * 8 + h) * Sn) * 32 + c4 * 8;

    f32x2 acc0 = {0.f, 0.f}, acc1 = {0.f, 0.f}, acc2a = {0.f, 0.f}, acc3 = {0.f, 0.f};

#pragma unroll
    for (int l = 0; l < 4; ++l) {
        const int W = sz[l];
        const float Wf = (float)W;
        const unsigned short* lptr = valh + (size_t)st[l] * 32;

        const int pl = l * 4 + c4;
        const float aw = s_attn[it][pl];
        const float fx = s_loc[it][pl * 2]     * Wf - 0.5f;
        const float fy = s_loc[it][pl * 2 + 1] * Wf - 0.5f;
        const float xf = floorf(fx), yf = floorf(fy);
        const float wx = fx - xf,  wy = fy - yf;
        const int x0 = (int)xf, y0 = (int)yf;
        const int x1 = x0 + 1,  y1 = y0 + 1;
        const float vx0 = (x0 >= 0 && x0 < W) ? 1.f : 0.f;
        const float vx1 = (x1 >= 0 && x1 < W) ? 1.f : 0.f;
        const float vy0 = (y0 >= 0 && y0 < W) ? 1.f : 0.f;
        const float vy1 = (y1 >= 0 && y1 < W) ? 1.f : 0.f;
        const int x0c = min(max(x0, 0), W - 1);
        const int x1c = min(max(x1, 0), W - 1);
        const int y0c = min(max(y0, 0), W - 1);
        const int y1c = min(max(y1, 0), W - 1);

        const float w00 = aw * (1.f - wx) * (1.f - wy) * vx0 * vy0;
        const float w01 = aw * wx         * (1.f - wy) * vx1 * vy0;
        const float w10 = aw * (1.f - wx) * wy         * vx0 * vy1;
        const float w11 = aw * wx         * wy         * vx1 * vy1;
        const int a00 = y0c * W + x0c;
        const int a01 = y0c * W + x1c;
        const int a10 = y1c * W + x0c;
        const int a11 = y1c * W + x1c;

#pragma unroll
        for (int p = 0; p < 4; ++p) {
            const float u00 = __shfl(w00, p, 4);
            const float u01 = __shfl(w01, p, 4);
            const float u10 = __shfl(w10, p, 4);
            const float u11 = __shfl(w11, p, 4);
            const int   e00 = __shfl(a00, p, 4);
            const int   e01 = __shfl(a01, p, 4);
            const int   e10 = __shfl(a10, p, 4);
            const int   e11 = __shfl(a11, p, 4);

            const uint4 q00 = *(const uint4*)(lptr + (size_t)e00 * 32);
            const uint4 q01 = *(const uint4*)(lptr + (size_t)e01 * 32);
            const uint4 q10 = *(const uint4*)(lptr + (size_t)e10 * 32);
            const uint4 q11 = *(const uint4*)(lptr + (size_t)e11 * 32);

            f32x2 wv;
            wv.x = u00; wv.y = u00;
            acc0 += wv * cvt2(q00.x); acc1 += wv * cvt2(q00.y);
            acc2a += wv * cvt2(q00.z); acc3 += wv * cvt2(q00.w);
            wv.x = u01; wv.y = u01;
            acc0 += wv * cvt2(q01.x); acc1 += wv * cvt2(q01.y);
            acc2a += wv * cvt2(q01.z); acc3 += wv * cvt2(q01.w);
            wv.x = u10; wv.y = u10;
            acc0 += wv * cvt2(q10.x); acc1 += wv * cvt2(q10.y);
            acc2a += wv * cvt2(q10.z); acc3 += wv * cvt2(q10.w);
            wv.x = u11; wv.y = u11;
            acc0 += wv * cvt2(q11.x); acc1 += wv * cvt2(q11.y);
            acc2a += wv * cvt2(q11.z); acc3 += wv * cvt2(q11.w);
        }
    }

    uint4 o;
    o.x = (unsigned int)f2bf(acc0.x) | ((unsigned int)f2bf(acc0.y) << 16);
    o.y = (unsigned int)f2bf(acc1.x) | ((unsigned int)f2bf(acc1.y) << 16);
    o.z = (unsigned int)f2bf(acc2a.x) | ((unsigned int)f2bf(acc2a.y) << 16);
    o.w = (unsigned int)f2bf(acc3.x) | ((unsigned int)f2bf(acc3.y) << 16);
    *(uint4*)(accb + (size_t)t * 256 + h * 32 + c4 * 8) = o;
}

// ---------------- launch ----------------
extern "C" void kernel_launch(void* const* d_in, const int* in_sizes, int n_in,
                              void* d_out, int out_size, void* d_ws, size_t ws_size,
                              hipStream_t stream) {
    const float* src    = (const float*)d_in[0];
    const float* pos    = (const float*)d_in[1];
    const float* refpts = (const float*)d_in[2];
    const float* W_off  = (const float*)d_in[5];
    const float* b_off  = (const float*)d_in[6];
    const float* W_attn = (const float*)d_in[7];
    const float* b_attn = (const float*)d_in[8];
    const float* W_val  = (const float*)d_in[9];
    const float* b_val  = (const float*)d_in[10];
    const float* W_out  = (const float*)d_in[11];
    const float* b_out  = (const float*)d_in[12];
    const float* W_ffn1 = (const float*)d_in[13];
    const float* b_ffn1 = (const float*)d_in[14];
    const float* W_ffn2 = (const float*)d_in[15];
    const float* b_ffn2 = (const float*)d_in[16];
    const float* ln1_g  = (const float*)d_in[17];
    const float* ln1_b  = (const float*)d_in[18];
    const float* ln2_g  = (const float*)d_in[19];
    const float* ln2_b  = (const float*)d_in[20];

    char* ws = (char*)d_ws;

    unsigned short* wT      = (unsigned short*)ws;
    unsigned short* WprojT  = wT + 0;        // 640x256
    unsigned short* WoutT   = wT + 163840;   // 256x256
    unsigned short* Wffn1T  = wT + 229376;   // 1024x256
    unsigned short* Wffn2T  = wT + 491520;   // 256x1024

    constexpr size_t SZ_TOK_BF = (size_t)BS * 256 * 2;
    constexpr size_t SZ_TOK_F  = (size_t)BS * 256 * 4;
    const size_t o = 2u * 1024 * 1024;
    unsigned short* srcb  = (unsigned short*)(ws + o);                         // later: x_bf16
    unsigned short* qb    = (unsigned short*)(ws + o + SZ_TOK_BF);             // later: acc_bf16
    unsigned short* valb  = (unsigned short*)(ws + o + 2 * SZ_TOK_BF);         // later: h_bf16 overlay
    float*          locf  = (float*)(ws + o + 3 * SZ_TOK_BF);
    float*          attnf = (float*)(ws + o + 3 * SZ_TOK_BF + SZ_TOK_F);
    unsigned short* hb    = valb;   // ffn hidden overlays value+loc+attn
    unsigned short* xb    = srcb;
    unsigned short* accb  = qb;

    float* out = (float*)d_out;

    // 1) weights
    transpose_all<<<(753664 + 255) / 256, 256, 0, stream>>>(
        W_val, W_off, W_attn, W_out, W_ffn1, W_ffn2, wT);

    // 2) activations prep (float4-vectorized)
    prep_q<<<2048, 256, 0, stream>>>(src, pos, srcb, qb, BS * 256);

    // 3) fused projections: value(head-major) + loc + attn(softmax), persistent-B
    gemm_proj<<<dim3(5, 85), 256, 0, stream>>>(
        srcb, qb, WprojT, b_val, b_off, b_attn, refpts, valb, locf, attnf);

    // 4) deformable bilinear sampling + weighted sum (head-partitioned per XCD)
    deform_sample<<<BS / 8, 256, 0, stream>>>(valb, locf, attnf, accb);

    // 5) out-proj + residual(src) + LN1 -> out fp32 + xb bf16  (M=128, 512 thr)
    gemm_ln<0, 256><<<BS / 128, 512, 0, stream>>>(
        accb, WoutT, b_out, ln1_g, ln1_b, src, out, xb);

    // 6) FFN1 + relu -> bf16, persistent-B
    gemm_ffn1<<<dim3(8, 85), 256, 0, stream>>>(xb, Wffn1T, b_ffn1, hb);

    // 7) FFN2 + residual(x=out) + LN2 -> out fp32 (final)  (M=128, 512 thr)
    gemm_ln<1, 1024><<<BS / 128, 512, 0, stream>>>(
        hb, Wffn2T, b_ffn2, ln2_g, ln2_b, out, out, nullptr);
}

// Round 8
// 470.251 us; speedup vs baseline: 1.8316x; 1.1937x over previous
//
#include <hip/hip_runtime.h>
#include <stdint.h>
#include <stddef.h>

// ---------------- problem constants ----------------
constexpr int Dm  = 256;
constexpr int NH  = 8;
constexpr int NL  = 4;
constexpr int NP  = 4;
constexpr int DFF = 1024;
constexpr int Bb  = 2;
constexpr int Sn  = 21760;            // 128*128 + 64*64 + 32*32 + 16*16
constexpr int BS  = Bb * Sn;          // 43520  (= 340 * 128 exactly)
constexpr int DH  = Dm / NH;          // 32

// ---------------- small helpers ----------------
__device__ __forceinline__ unsigned short f2bf(float f) {
    union { float f; unsigned int u; } v; v.f = f;
    unsigned int u = v.u;
    unsigned int r = u + 0x7FFFu + ((u >> 16) & 1u);   // round-nearest-even
    return (unsigned short)(r >> 16);
}

typedef float  f32x4  __attribute__((ext_vector_type(4)));
typedef float  f32x2  __attribute__((ext_vector_type(2)));
typedef __bf16 bf16x8 __attribute__((ext_vector_type(8)));

// unpack 2 bf16 (packed in u32) -> float2
__device__ __forceinline__ f32x2 cvt2(unsigned int u) {
    union { unsigned int u; float f; } lo, hi;
    lo.u = u << 16; hi.u = u & 0xFFFF0000u;
    f32x2 r; r.x = lo.f; r.y = hi.f; return r;
}

// address-space helpers for global_load_lds
typedef const __attribute__((address_space(1))) unsigned int GU;
typedef __attribute__((address_space(3))) unsigned int LU;
__device__ __forceinline__ void g2lds16(const void* g, void* l) {
    __builtin_amdgcn_global_load_lds((GU*)g, (LU*)l, 16, 0, 0);
}

// ---------------- all weights: convert + transpose in ONE kernel ----------------
// wT element layout (all N-major, [n][k]):
//   WprojT @0       : 640 x 256  (cols 0-255 W_val, 256-511 W_off, 512-639 W_attn)
//   WoutT  @163840  : 256 x 256
//   Wffn1T @229376  : 1024 x 256
//   Wffn2T @491520  : 256 x 1024
__global__ void transpose_all(const float* __restrict__ W_val, const float* __restrict__ W_off,
                              const float* __restrict__ W_attn, const float* __restrict__ W_out,
                              const float* __restrict__ W_ffn1, const float* __restrict__ W_ffn2,
                              unsigned short* __restrict__ wT) {
    int i = blockIdx.x * 256 + threadIdx.x;
    float v;
    if (i < 163840) {                       // proj block
        int n = i >> 8, k = i & 255;
        if      (n < 256) v = W_val[(size_t)k * 256 + n];
        else if (n < 512) v = W_off[(size_t)k * 256 + (n - 256)];
        else              v = W_attn[(size_t)k * 128 + (n - 512)];
    } else if (i < 229376) {
        int j = i - 163840, n = j >> 8, k = j & 255;
        v = W_out[(size_t)k * 256 + n];
    } else if (i < 491520) {
        int j = i - 229376, n = j >> 8, k = j & 255;
        v = W_ffn1[(size_t)k * 1024 + n];
    } else if (i < 753664) {
        int j = i - 491520, n = j >> 10, k = j & 1023;
        v = W_ffn2[(size_t)k * 256 + n];
    } else return;
    wT[i] = f2bf(v);
}

// ---------------- q = src+pos (bf16), src (bf16), float4-vectorized ----------------
__global__ void prep_q(const float* __restrict__ src, const float* __restrict__ pos,
                       unsigned short* __restrict__ srcb, unsigned short* __restrict__ qb,
                       int ntot) {
    for (int i = (blockIdx.x * blockDim.x + threadIdx.x) * 4; i < ntot;
         i += gridDim.x * blockDim.x * 4) {
        const float4 s = *(const float4*)&src[i];
        const float4 p = *(const float4*)&pos[i];
        ushort4 sb, qb4;
        sb.x = f2bf(s.x); sb.y = f2bf(s.y); sb.z = f2bf(s.z); sb.w = f2bf(s.w);
        qb4.x = f2bf(s.x + p.x); qb4.y = f2bf(s.y + p.y);
        qb4.z = f2bf(s.z + p.z); qb4.w = f2bf(s.w + p.w);
        *(ushort4*)&srcb[i] = sb;
        *(ushort4*)&qb[i]   = qb4;
    }
}

// ---------------- fused projection GEMM: value + offsets + attn(softmax) ----------------
// 128x128 tiles, grid (5, 340) — R1-verified geometry. v8 change: K-step 32 -> 64.
// Two 32-k panels staged per barrier pair (each panel's layout byte-identical to R1's
// single panel; panel0 = k0..k0+31, panel1 = k0+32..k0+63, ascending k order).
// Halves the vmcnt(0) barrier drains: 8 -> 4 per block.
__global__ __launch_bounds__(256)
void gemm_proj(const unsigned short* __restrict__ srcb,
               const unsigned short* __restrict__ qb,
               const unsigned short* __restrict__ WprojT,
               const float* __restrict__ b_val, const float* __restrict__ b_off,
               const float* __restrict__ b_attn, const float* __restrict__ refpts,
               unsigned short* __restrict__ valb, float* __restrict__ locf,
               float* __restrict__ attnf)
{
    __shared__ __align__(16) unsigned short As[2][128 * 32];   // 2 panels x 8 KB
    __shared__ __align__(16) unsigned short Bs[2][128 * 32];   // 2 panels x 8 KB

    const int tid  = threadIdx.x;
    const int lane = tid & 63;
    const int w    = tid >> 6;
    const int quad = lane >> 4;
    const int r16  = lane & 15;
    const int wr   = w >> 1, wc = w & 1;
    const int bm   = blockIdx.y, bn = blockIdx.x;

    const unsigned short* A  = (bn < 2) ? srcb : qb;
    const unsigned short* BT = WprojT + (size_t)bn * 128 * 256;

    const int sr = tid >> 2;
    const int sw = (((tid & 3) ^ ((tid >> 3) & 3)) << 3);
    const int qx = ((quad ^ ((r16 >> 1) & 3)) << 3);

    const unsigned short* gA0 = A  + (size_t)(bm * 128 + sr)      * 256 + sw;
    const unsigned short* gA1 = A  + (size_t)(bm * 128 + sr + 64) * 256 + sw;
    const unsigned short* gB0 = BT + (size_t)(sr)      * 256 + sw;
    const unsigned short* gB1 = BT + (size_t)(sr + 64) * 256 + sw;

    char* AsB = (char*)As;
    char* BsB = (char*)Bs;
    const int woff = w * 1024;

    f32x4 acc[4][4] = {};

    for (int k0 = 0; k0 < 256; k0 += 64) {
        __syncthreads();
        // panel 0 (k0 .. k0+31)
        g2lds16(gA0 + k0,      AsB + woff);
        g2lds16(gA1 + k0,      AsB + 4096 + woff);
        g2lds16(gB0 + k0,      BsB + woff);
        g2lds16(gB1 + k0,      BsB + 4096 + woff);
        // panel 1 (k0+32 .. k0+63)
        g2lds16(gA0 + k0 + 32, AsB + 8192 + woff);
        g2lds16(gA1 + k0 + 32, AsB + 12288 + woff);
        g2lds16(gB0 + k0 + 32, BsB + 8192 + woff);
        g2lds16(gB1 + k0 + 32, BsB + 12288 + woff);
        __syncthreads();

#pragma unroll
        for (int p = 0; p < 2; ++p) {
            const unsigned short* Ac = As[p];
            const unsigned short* Bc = Bs[p];
            bf16x8 af[4], bfr[4];
#pragma unroll
            for (int mt = 0; mt < 4; ++mt)
                af[mt] = *(const bf16x8*)&Ac[(wr * 64 + mt * 16 + r16) * 32 + qx];
#pragma unroll
            for (int nt = 0; nt < 4; ++nt)
                bfr[nt] = *(const bf16x8*)&Bc[(wc * 64 + nt * 16 + r16) * 32 + qx];
#pragma unroll
            for (int mt = 0; mt < 4; ++mt)
#pragma unroll
                for (int nt = 0; nt < 4; ++nt)
                    acc[mt][nt] = __builtin_amdgcn_mfma_f32_16x16x32_bf16(
                        af[mt], bfr[nt], acc[mt][nt], 0, 0, 0);
        }
    }

    const int mbase = bm * 128 + wr * 64 + quad * 4;
    const int nbase = bn * 128 + wc * 64 + r16;   // global col in 0..639
#pragma unroll
    for (int mt = 0; mt < 4; ++mt) {
#pragma unroll
        for (int nt = 0; nt < 4; ++nt) {
            const int col = nbase + nt * 16;
#pragma unroll
            for (int r = 0; r < 4; ++r) {
                const int row = mbase + mt * 16 + r;
                const float v = acc[mt][nt][r];
                if (bn < 2) {
                    // value, head-major: [b][h][pos][32ch]
                    const int b = (row >= Sn) ? 1 : 0;
                    const int srow = row - b * Sn;
                    const int h = col >> 5, ch = col & 31;
                    valb[(((size_t)b * 8 + h) * Sn + srow) * 32 + ch] =
                        f2bf(v + b_val[col]);
                } else if (bn < 4) {
                    const int c2 = col - 256;
                    const int c = c2 & 1;
                    const int l = (c2 >> 3) & 3;
                    const float invn = 1.f / (float)(128 >> l);
                    const float rp = refpts[(size_t)row * 8 + l * 2 + c];
                    locf[(size_t)row * 256 + c2] = rp + (v + b_off[c2]) * invn;
                } else {
                    const int c2 = col - 512;   // 0..127
                    float x = v + b_attn[c2];
                    float mx = x;
                    mx = fmaxf(mx, __shfl_xor(mx, 1));
                    mx = fmaxf(mx, __shfl_xor(mx, 2));
                    mx = fmaxf(mx, __shfl_xor(mx, 4));
                    mx = fmaxf(mx, __shfl_xor(mx, 8));
                    float e = __expf(x - mx);
                    float s = e;
                    s += __shfl_xor(s, 1);
                    s += __shfl_xor(s, 2);
                    s += __shfl_xor(s, 4);
                    s += __shfl_xor(s, 8);
                    attnf[(size_t)row * 128 + c2] = e / s;
                }
            }
        }
    }
}

// ---------------- ffn1 GEMM: 128x128 tiles, K-step 64, relu -> bf16 ----------------
__global__ __launch_bounds__(256)
void gemm_ffn1(const unsigned short* __restrict__ A,
               const unsigned short* __restrict__ BT,
               const float* __restrict__ bias,
               unsigned short* __restrict__ outp)
{
    __shared__ __align__(16) unsigned short As[2][128 * 32];
    __shared__ __align__(16) unsigned short Bs[2][128 * 32];

    const int tid  = threadIdx.x;
    const int lane = tid & 63;
    const int w    = tid >> 6;
    const int quad = lane >> 4;
    const int r16  = lane & 15;
    const int wr   = w >> 1, wc = w & 1;
    const int bm   = blockIdx.y, bn = blockIdx.x;

    const int sr = tid >> 2;
    const int sw = (((tid & 3) ^ ((tid >> 3) & 3)) << 3);
    const int qx = ((quad ^ ((r16 >> 1) & 3)) << 3);

    const unsigned short* gA0 = A  + (size_t)(bm * 128 + sr)      * 256 + sw;
    const unsigned short* gA1 = A  + (size_t)(bm * 128 + sr + 64) * 256 + sw;
    const unsigned short* gB0 = BT + (size_t)(bn * 128 + sr)      * 256 + sw;
    const unsigned short* gB1 = BT + (size_t)(bn * 128 + sr + 64) * 256 + sw;

    char* AsB = (char*)As;
    char* BsB = (char*)Bs;
    const int woff = w * 1024;

    f32x4 acc[4][4] = {};

    for (int k0 = 0; k0 < 256; k0 += 64) {
        __syncthreads();
        g2lds16(gA0 + k0,      AsB + woff);
        g2lds16(gA1 + k0,      AsB + 4096 + woff);
        g2lds16(gB0 + k0,      BsB + woff);
        g2lds16(gB1 + k0,      BsB + 4096 + woff);
        g2lds16(gA0 + k0 + 32, AsB + 8192 + woff);
        g2lds16(gA1 + k0 + 32, AsB + 12288 + woff);
        g2lds16(gB0 + k0 + 32, BsB + 8192 + woff);
        g2lds16(gB1 + k0 + 32, BsB + 12288 + woff);
        __syncthreads();

#pragma unroll
        for (int p = 0; p < 2; ++p) {
            const unsigned short* Ac = As[p];
            const unsigned short* Bc = Bs[p];
            bf16x8 af[4], bfr[4];
#pragma unroll
            for (int mt = 0; mt < 4; ++mt)
                af[mt] = *(const bf16x8*)&Ac[(wr * 64 + mt * 16 + r16) * 32 + qx];
#pragma unroll
            for (int nt = 0; nt < 4; ++nt)
                bfr[nt] = *(const bf16x8*)&Bc[(wc * 64 + nt * 16 + r16) * 32 + qx];
#pragma unroll
            for (int mt = 0; mt < 4; ++mt)
#pragma unroll
                for (int nt = 0; nt < 4; ++nt)
                    acc[mt][nt] = __builtin_amdgcn_mfma_f32_16x16x32_bf16(
                        af[mt], bfr[nt], acc[mt][nt], 0, 0, 0);
        }
    }

    const int mbase = bm * 128 + wr * 64 + quad * 4;
    const int nbase = bn * 128 + wc * 64 + r16;
#pragma unroll
    for (int mt = 0; mt < 4; ++mt) {
#pragma unroll
        for (int nt = 0; nt < 4; ++nt) {
            const int col = nbase + nt * 16;
#pragma unroll
            for (int r = 0; r < 4; ++r) {
                const int row = mbase + mt * 16 + r;
                float t = acc[mt][nt][r] + bias[col];
                outp[(size_t)row * 1024 + col] = f2bf(t > 0.f ? t : 0.f);
            }
        }
    }
}

// ---------------- GEMM + residual + LayerNorm fused (64x256 tile, K-step 64) ----------
// MODE 0: out-proj: t = acc + bias + resid(src);  y = LN1(t); out=y fp32, xb=bf16(y)
// MODE 1: ffn2:     t = acc + bias + resid(x=d_out); y = LN2(t); out=y fp32
template<int MODE, int K>
__global__ __launch_bounds__(256)
void gemm_ln(const unsigned short* __restrict__ A,
             const unsigned short* __restrict__ BT,
             const float* __restrict__ bias,
             const float* __restrict__ gamma, const float* __restrict__ beta,
             const float* resid,
             float* out, unsigned short* __restrict__ xb)
{
    __shared__ __align__(16) unsigned short As[2][64 * 32];    // 2 x 4 KB
    __shared__ __align__(16) unsigned short Bs[2][256 * 32];   // 2 x 16 KB
    __shared__ float red[2][64][2];

    const int tid  = threadIdx.x;
    const int lane = tid & 63;
    const int w    = tid >> 6;
    const int quad = lane >> 4;
    const int r16  = lane & 15;
    const int wr   = w >> 1, wc = w & 1;   // wave tile 32 rows x 128 cols
    const int bm   = blockIdx.x;

    const int sr = tid >> 2;          // 0..63
    const int sw = (((tid & 3) ^ ((tid >> 3) & 3)) << 3);
    const int qx = ((quad ^ ((r16 >> 1) & 3)) << 3);

    const unsigned short* gA  = A  + (size_t)(bm * 64 + sr) * K + sw;
    const unsigned short* gB0 = BT + (size_t)(sr)       * K + sw;
    const unsigned short* gB1 = BT + (size_t)(sr + 64)  * K + sw;
    const unsigned short* gB2 = BT + (size_t)(sr + 128) * K + sw;
    const unsigned short* gB3 = BT + (size_t)(sr + 192) * K + sw;

    char* AsB = (char*)As;
    char* BsB = (char*)Bs;
    const int woff = w * 1024;

    f32x4 acc[2][8] = {};

    for (int k0 = 0; k0 < K; k0 += 64) {
        __syncthreads();
        // panel 0
        g2lds16(gA  + k0,      AsB + woff);
        g2lds16(gB0 + k0,      BsB + woff);
        g2lds16(gB1 + k0,      BsB + 4096  + woff);
        g2lds16(gB2 + k0,      BsB + 8192  + woff);
        g2lds16(gB3 + k0,      BsB + 12288 + woff);
        // panel 1
        g2lds16(gA  + k0 + 32, AsB + 4096  + woff);
        g2lds16(gB0 + k0 + 32, BsB + 16384 + woff);
        g2lds16(gB1 + k0 + 32, BsB + 20480 + woff);
        g2lds16(gB2 + k0 + 32, BsB + 24576 + woff);
        g2lds16(gB3 + k0 + 32, BsB + 28672 + woff);
        __syncthreads();

#pragma unroll
        for (int p = 0; p < 2; ++p) {
            const unsigned short* Ac = As[p];
            const unsigned short* Bc = Bs[p];
            bf16x8 af[2], bfr[8];
#pragma unroll
            for (int mt = 0; mt < 2; ++mt)
                af[mt] = *(const bf16x8*)&Ac[(wr * 32 + mt * 16 + r16) * 32 + qx];
#pragma unroll
            for (int nt = 0; nt < 8; ++nt)
                bfr[nt] = *(const bf16x8*)&Bc[(wc * 128 + nt * 16 + r16) * 32 + qx];
#pragma unroll
            for (int mt = 0; mt < 2; ++mt)
#pragma unroll
                for (int nt = 0; nt < 8; ++nt)
                    acc[mt][nt] = __builtin_amdgcn_mfma_f32_16x16x32_bf16(
                        af[mt], bfr[nt], acc[mt][nt], 0, 0, 0);
        }
    }

    // t = acc + bias + resid  (in place)
    const int rl_base = wr * 32 + quad * 4;
    const int cbase   = wc * 128 + r16;
#pragma unroll
    for (int mt = 0; mt < 2; ++mt)
#pragma unroll
        for (int nt = 0; nt < 8; ++nt) {
            const int col = cbase + nt * 16;
#pragma unroll
            for (int r = 0; r < 4; ++r) {
                const int rowl = rl_base + mt * 16 + r;
                const size_t gix = (size_t)(bm * 64 + rowl) * 256 + col;
                acc[mt][nt][r] += bias[col] + resid[gix];
            }
        }

    // per-row sums over this wave's 128 cols, then cross-wave via LDS
#pragma unroll
    for (int mt = 0; mt < 2; ++mt)
#pragma unroll
        for (int r = 0; r < 4; ++r) {
            float s = 0.f, s2 = 0.f;
#pragma unroll
            for (int nt = 0; nt < 8; ++nt) {
                const float v = acc[mt][nt][r];
                s += v; s2 += v * v;
            }
            s  += __shfl_xor(s, 1);  s2 += __shfl_xor(s2, 1);
            s  += __shfl_xor(s, 2);  s2 += __shfl_xor(s2, 2);
            s  += __shfl_xor(s, 4);  s2 += __shfl_xor(s2, 4);
            s  += __shfl_xor(s, 8);  s2 += __shfl_xor(s2, 8);
            if (r16 == 0) {
                const int rowl = rl_base + mt * 16 + r;
                red[wc][rowl][0] = s;
                red[wc][rowl][1] = s2;
            }
        }
    __syncthreads();

#pragma unroll
    for (int mt = 0; mt < 2; ++mt)
#pragma unroll
        for (int r = 0; r < 4; ++r) {
            const int rowl = rl_base + mt * 16 + r;
            const float ts  = red[0][rowl][0] + red[1][rowl][0];
            const float ts2 = red[0][rowl][1] + red[1][rowl][1];
            const float mu  = ts * (1.f / 256.f);
            const float var = ts2 * (1.f / 256.f) - mu * mu;
            const float inv = rsqrtf(var + 1e-5f);
#pragma unroll
            for (int nt = 0; nt < 8; ++nt) {
                const int col = cbase + nt * 16;
                const size_t gix = (size_t)(bm * 64 + rowl) * 256 + col;
                const float y = (acc[mt][nt][r] - mu) * inv * gamma[col] + beta[col];
                out[gix] = y;
                if constexpr (MODE == 0) xb[gix] = f2bf(y);
            }
        }
}

// ---------------- deformable sampling, v5: head-partitioned (XCD-local value) ----------
__global__ __launch_bounds__(256)
void deform_sample(const unsigned short* __restrict__ val,   // (B,8,Sn,32) bf16
                   const float* __restrict__ loc,            // (BS,256) fp32  (h,l,p,c)
                   const float* __restrict__ attn,           // (BS,128) fp32  (h,l,p)
                   unsigned short* __restrict__ accb)        // (BS,256) bf16
{
    __shared__ float s_loc[64][33];
    __shared__ float s_attn[64][17];

    const int tid   = threadIdx.x;
    const int xcd   = blockIdx.x & 7;       // round-robin XCD id
    const int chunk = blockIdx.x >> 3;      // 0..679
    const int b     = chunk & 1;
    const int h     = xcd;                  // one head per XCD
    const int tc    = chunk >> 1;           // 0..339
    const int tbase = b * Sn + tc * 64;

    for (int i = tid; i < 64 * 32; i += 256) {
        const int tok = i >> 5, k = i & 31;
        s_loc[tok][k] = loc[(size_t)(tbase + tok) * 256 + h * 32 + k];
    }
    for (int i = tid; i < 64 * 16; i += 256) {
        const int tok = i >> 4, k = i & 15;
        s_attn[tok][k] = attn[(size_t)(tbase + tok) * 128 + h * 16 + k];
    }
    __syncthreads();

    const int c4 = tid & 3;                 // channel group (8 ch = 16 B)
    const int it = tid >> 2;                // token in block, 0..63
    const int t  = tbase + it;

    const int sz[4] = {128, 64, 32, 16};
    const int st[4] = {0, 16384, 20480, 21504};

    const unsigned short* valh = val + ((size_t)(b * 8 + h) * Sn) * 32 + c4 * 8;

    f32x2 acc0 = {0.f, 0.f}, acc1 = {0.f, 0.f}, acc2a = {0.f, 0.f}, acc3 = {0.f, 0.f};

#pragma unroll
    for (int l = 0; l < 4; ++l) {
        const int W = sz[l];
        const float Wf = (float)W;
        const unsigned short* lptr = valh + (size_t)st[l] * 32;

        const int pl = l * 4 + c4;
        const float aw = s_attn[it][pl];
        const float fx = s_loc[it][pl * 2]     * Wf - 0.5f;
        const float fy = s_loc[it][pl * 2 + 1] * Wf - 0.5f;
        const float xf = floorf(fx), yf = floorf(fy);
        const float wx = fx - xf,  wy = fy - yf;
        const int x0 = (int)xf, y0 = (int)yf;
        const int x1 = x0 + 1,  y1 = y0 + 1;
        const float vx0 = (x0 >= 0 && x0 < W) ? 1.f : 0.f;
        const float vx1 = (x1 >= 0 && x1 < W) ? 1.f : 0.f;
        const float vy0 = (y0 >= 0 && y0 < W) ? 1.f : 0.f;
        const float vy1 = (y1 >= 0 && y1 < W) ? 1.f : 0.f;
        const int x0c = min(max(x0, 0), W - 1);
        const int x1c = min(max(x1, 0), W - 1);
        const int y0c = min(max(y0, 0), W - 1);
        const int y1c = min(max(y1, 0), W - 1);

        const float w00 = aw * (1.f - wx) * (1.f - wy) * vx0 * vy0;
        const float w01 = aw * wx         * (1.f - wy) * vx1 * vy0;
        const float w10 = aw * (1.f - wx) * wy         * vx0 * vy1;
        const float w11 = aw * wx         * wy         * vx1 * vy1;
        const int a00 = y0c * W + x0c;
        const int a01 = y0c * W + x1c;
        const int a10 = y1c * W + x0c;
        const int a11 = y1c * W + x1c;

#pragma unroll
        for (int p = 0; p < 4; ++p) {
            const float u00 = __shfl(w00, p, 4);
            const float u01 = __shfl(w01, p, 4);
            const float u10 = __shfl(w10, p, 4);
            const float u11 = __shfl(w11, p, 4);
            const int   e00 = __shfl(a00, p, 4);
            const int   e01 = __shfl(a01, p, 4);
            const int   e10 = __shfl(a10, p, 4);
            const int   e11 = __shfl(a11, p, 4);

            const uint4 q00 = *(const uint4*)(lptr + (size_t)e00 * 32);
            const uint4 q01 = *(const uint4*)(lptr + (size_t)e01 * 32);
            const uint4 q10 = *(const uint4*)(lptr + (size_t)e10 * 32);
            const uint4 q11 = *(const uint4*)(lptr + (size_t)e11 * 32);

            f32x2 wv;
            wv.x = u00; wv.y = u00;
            acc0 += wv * cvt2(q00.x); acc1 += wv * cvt2(q00.y);
            acc2a += wv * cvt2(q00.z); acc3 += wv * cvt2(q00.w);
            wv.x = u01; wv.y = u01;
            acc0 += wv * cvt2(q01.x); acc1 += wv * cvt2(q01.y);
            acc2a += wv * cvt2(q01.z); acc3 += wv * cvt2(q01.w);
            wv.x = u10; wv.y = u10;
            acc0 += wv * cvt2(q10.x); acc1 += wv * cvt2(q10.y);
            acc2a += wv * cvt2(q10.z); acc3 += wv * cvt2(q10.w);
            wv.x = u11; wv.y = u11;
            acc0 += wv * cvt2(q11.x); acc1 += wv * cvt2(q11.y);
            acc2a += wv * cvt2(q11.z); acc3 += wv * cvt2(q11.w);
        }
    }

    uint4 o;
    o.x = (unsigned int)f2bf(acc0.x) | ((unsigned int)f2bf(acc0.y) << 16);
    o.y = (unsigned int)f2bf(acc1.x) | ((unsigned int)f2bf(acc1.y) << 16);
    o.z = (unsigned int)f2bf(acc2a.x) | ((unsigned int)f2bf(acc2a.y) << 16);
    o.w = (unsigned int)f2bf(acc3.x) | ((unsigned int)f2bf(acc3.y) << 16);
    *(uint4*)(accb + (size_t)t * 256 + h * 32 + c4 * 8) = o;
}

// ---------------- launch ----------------
extern "C" void kernel_launch(void* const* d_in, const int* in_sizes, int n_in,
                              void* d_out, int out_size, void* d_ws, size_t ws_size,
                              hipStream_t stream) {
    const float* src    = (const float*)d_in[0];
    const float* pos    = (const float*)d_in[1];
    const float* refpts = (const float*)d_in[2];
    const float* W_off  = (const float*)d_in[5];
    const float* b_off  = (const float*)d_in[6];
    const float* W_attn = (const float*)d_in[7];
    const float* b_attn = (const float*)d_in[8];
    const float* W_val  = (const float*)d_in[9];
    const float* b_val  = (const float*)d_in[10];
    const float* W_out  = (const float*)d_in[11];
    const float* b_out  = (const float*)d_in[12];
    const float* W_ffn1 = (const float*)d_in[13];
    const float* b_ffn1 = (const float*)d_in[14];
    const float* W_ffn2 = (const float*)d_in[15];
    const float* b_ffn2 = (const float*)d_in[16];
    const float* ln1_g  = (const float*)d_in[17];
    const float* ln1_b  = (const float*)d_in[18];
    const float* ln2_g  = (const float*)d_in[19];
    const float* ln2_b  = (const float*)d_in[20];

    char* ws = (char*)d_ws;

    unsigned short* wT      = (unsigned short*)ws;
    unsigned short* WprojT  = wT + 0;        // 640x256
    unsigned short* WoutT   = wT + 163840;   // 256x256
    unsigned short* Wffn1T  = wT + 229376;   // 1024x256
    unsigned short* Wffn2T  = wT + 491520;   // 256x1024

    constexpr size_t SZ_TOK_BF = (size_t)BS * 256 * 2;
    constexpr size_t SZ_TOK_F  = (size_t)BS * 256 * 4;
    const size_t o = 2u * 1024 * 1024;
    unsigned short* srcb  = (unsigned short*)(ws + o);                         // later: x_bf16
    unsigned short* qb    = (unsigned short*)(ws + o + SZ_TOK_BF);             // later: acc_bf16
    unsigned short* valb  = (unsigned short*)(ws + o + 2 * SZ_TOK_BF);         // later: h_bf16 overlay
    float*          locf  = (float*)(ws + o + 3 * SZ_TOK_BF);
    float*          attnf = (float*)(ws + o + 3 * SZ_TOK_BF + SZ_TOK_F);
    unsigned short* hb    = valb;   // ffn hidden overlays value+loc+attn
    unsigned short* xb    = srcb;
    unsigned short* accb  = qb;

    float* out = (float*)d_out;

    // 1) weights
    transpose_all<<<(753664 + 255) / 256, 256, 0, stream>>>(
        W_val, W_off, W_attn, W_out, W_ffn1, W_ffn2, wT);

    // 2) activations prep (float4-vectorized)
    prep_q<<<2048, 256, 0, stream>>>(src, pos, srcb, qb, BS * 256);

    // 3) fused projections: value(head-major) + loc + attn(softmax)
    gemm_proj<<<dim3(5, BS / 128), 256, 0, stream>>>(
        srcb, qb, WprojT, b_val, b_off, b_attn, refpts, valb, locf, attnf);

    // 4) deformable bilinear sampling + weighted sum (head-partitioned per XCD)
    deform_sample<<<BS / 8, 256, 0, stream>>>(valb, locf, attnf, accb);

    // 5) out-proj + residual(src) + LN1 -> out fp32 + xb bf16
    gemm_ln<0, 256><<<BS / 64, 256, 0, stream>>>(
        accb, WoutT, b_out, ln1_g, ln1_b, src, out, xb);

    // 6) FFN1 + relu -> bf16
    gemm_ffn1<<<dim3(8, BS / 128), 256, 0, stream>>>(xb, Wffn1T, b_ffn1, hb);

    // 7) FFN2 + residual(x=out) + LN2 -> out fp32 (final)
    gemm_ln<1, 1024><<<BS / 64, 256, 0, stream>>>(
        hb, Wffn2T, b_ffn2, ln2_g, ln2_b, out, out, nullptr);
}